// Round 10
// baseline (854.281 us; speedup 1.0000x reference)
//
#include <hip/hip_runtime.h>
#include <math.h>

#define NBATCH 8
#define NPTS 4096
#define NPOINT 1024
#define NSAMPLE 32
#define PTDIM 67        // 3 xyz + 64 feat
#define BIGF 1e10f

// DPP ctrl encodings (gfx9/CDNA)
#define DPP_QUAD_XOR1 0xB1   // quad_perm [1,0,3,2]
#define DPP_QUAD_XOR2 0x4E   // quad_perm [2,3,0,1]
#define DPP_ROW_HALF_MIRROR 0x141
#define DPP_ROW_MIRROR 0x140
#define DPP_ROW_BCAST15 0x142
#define DPP_ROW_BCAST31 0x143

template <int CTRL>
__device__ inline float dpp_mov_f(float v) {
  int i = __float_as_int(v);
  return __int_as_float(__builtin_amdgcn_update_dpp(i, i, CTRL, 0xf, 0xf, false));
}
template <int CTRL>
__device__ inline unsigned dpp_mov_u(unsigned v) {
  return (unsigned)__builtin_amdgcn_update_dpp((int)v, (int)v, CTRL, 0xf, 0xf, false);
}
template <int CTRL>
__device__ inline void dpp_min2(unsigned& hi, unsigned& lo) {
  unsigned nh = dpp_mov_u<CTRL>(hi);
  unsigned nl = dpp_mov_u<CTRL>(lo);
  bool take = (nh < hi) || (nh == hi && nl < lo);
  hi = take ? nh : hi;
  lo = take ? nl : lo;
}
__device__ inline unsigned fmap(float d) {
  unsigned b = __float_as_uint(d);
  return ((int)b < 0) ? ~b : (b | 0x80000000u);
}
#define FMAP_INF 0xFF800000u   // fmap(+INF)

__device__ inline float4 sel4(bool c, float4 a, float4 b) {
  return make_float4(c ? a.x : b.x, c ? a.y : b.y, c ? a.z : b.z, c ? a.w : b.w);
}

// 32-lane-group reductions: 4 VALU-DPP levels + ONE DS op (xor16) per value.
__device__ inline float red32_max(float v) {
  v = fmaxf(v, dpp_mov_f<DPP_QUAD_XOR1>(v));
  v = fmaxf(v, dpp_mov_f<DPP_QUAD_XOR2>(v));
  v = fmaxf(v, dpp_mov_f<DPP_ROW_HALF_MIRROR>(v));
  v = fmaxf(v, dpp_mov_f<DPP_ROW_MIRROR>(v));
  v = fmaxf(v, __shfl_xor(v, 16));
  return v;
}
__device__ inline float red32_sum(float v) {
  v += dpp_mov_f<DPP_QUAD_XOR1>(v);
  v += dpp_mov_f<DPP_QUAD_XOR2>(v);
  v += dpp_mov_f<DPP_ROW_HALF_MIRROR>(v);
  v += dpp_mov_f<DPP_ROW_MIRROR>(v);
  v += __shfl_xor(v, 16);
  return v;
}

// ---------------------------------------------------------------------------
// F1: fused FPS (blocks 0..7) + PROJ-MLP (blocks 8..71), as in R9.
// fps change: candidate coords fetched PRE-barrier (C[jmin], wave-uniform,
// latency hidden under the barrier wait) and carried through the slots, so
// the post-barrier chain is ONE LDS read burst (keys+coords) + cndmask select
// — the dependent C[f] roundtrip is gone. Selection keys unchanged.
// ---------------------------------------------------------------------------
struct __align__(16) Slot { float4 c; unsigned long long key; unsigned long long pad; };
struct FpsS {
  Slot slots[2][4];
  int cidxS[NPOINT];
  float4 C[NPTS];
};
struct ProjS {
  float As[131 * 128];
  float w0[64 * 64], w1[64 * 64], w2[128 * 64];
  float bb0[64], ss0[64], ee0[64];
  float bb1[64], ss1[64], ee1[64];
  float bb2[128], ss2[128], ee2[128];
};
#define F1_SMEM (sizeof(ProjS) > sizeof(FpsS) ? sizeof(ProjS) : sizeof(FpsS))

// Exact f32 replication of jnp: ((dx*dx+dy*dy)+dz*dz), min, argmax first-idx.
__device__ void fps_body(char* smemRaw, const float* __restrict__ pts,
                         int* __restrict__ cidx, float* __restrict__ X,
                         float* __restrict__ Y, float* __restrict__ Z) {
#pragma clang fp contract(off)
  FpsS* S = (FpsS*)smemRaw;
  const int b = blockIdx.x, tid = threadIdx.x;
  const int w = tid >> 6, lane = tid & 63;
  const float* pb = pts + (size_t)b * NPTS * PTDIM;
  float2 px2[8], py2[8], pz2[8];
  float dl[16];
  #pragma unroll
  for (int k = 0; k < 16; k++) {
    int j = tid + (k << 8);
    const float* pj = pb + (size_t)j * PTDIM;
    float x = pj[0], y = pj[1], z = pj[2];
    if (k & 1) { px2[k >> 1].y = x; py2[k >> 1].y = y; pz2[k >> 1].y = z; }
    else       { px2[k >> 1].x = x; py2[k >> 1].x = y; pz2[k >> 1].x = z; }
    S->C[j] = make_float4(x, y, z, 0.0f);
    X[b * NPTS + j] = x; Y[b * NPTS + j] = y; Z[b * NPTS + j] = z;  // SoA out
    dl[k] = BIGF;
  }
  __syncthreads();
  int f = 0;
  float4 c0 = S->C[0];
  float cx = c0.x, cy = c0.y, cz = c0.z;
  for (int t = 0; t < NPOINT; t++) {
    if (tid == 0) S->cidxS[t] = f;                 // emit BEFORE update
    float2 c2x = make_float2(cx, cx);
    float2 c2y = make_float2(cy, cy);
    float2 c2z = make_float2(cz, cz);
    #pragma unroll
    for (int m = 0; m < 8; m++) {
      float2 dx = px2[m] - c2x;
      float2 dy = py2[m] - c2y;
      float2 dz = pz2[m] - c2z;
      float2 d = (dx * dx + dy * dy) + dz * dz;    // pk ops, contract OFF
      dl[2 * m]     = fminf(dl[2 * m],     d.x);
      dl[2 * m + 1] = fminf(dl[2 * m + 1], d.y);
    }
    float u0 = fmaxf(dl[0], dl[1]),  u1 = fmaxf(dl[2], dl[3]);
    float u2 = fmaxf(dl[4], dl[5]),  u3 = fmaxf(dl[6], dl[7]);
    float u4 = fmaxf(dl[8], dl[9]),  u5 = fmaxf(dl[10], dl[11]);
    float u6 = fmaxf(dl[12], dl[13]), u7 = fmaxf(dl[14], dl[15]);
    float v0 = fmaxf(u0, u1), v1 = fmaxf(u2, u3);
    float v2 = fmaxf(u4, u5), v3 = fmaxf(u6, u7);
    float bv = fmaxf(fmaxf(v0, v1), fmaxf(v2, v3));
    float m = bv;
    m = fmaxf(m, dpp_mov_f<DPP_QUAD_XOR1>(m));
    m = fmaxf(m, dpp_mov_f<DPP_QUAD_XOR2>(m));
    m = fmaxf(m, dpp_mov_f<DPP_ROW_HALF_MIRROR>(m));
    m = fmaxf(m, dpp_mov_f<DPP_ROW_MIRROR>(m));
    m = fmaxf(m, dpp_mov_f<DPP_ROW_BCAST15>(m));
    m = fmaxf(m, dpp_mov_f<DPP_ROW_BCAST31>(m));   // lane63 = wave max
    unsigned wmaxbits = (unsigned)__builtin_amdgcn_readlane(__float_as_int(m), 63);
    // min index among holders (bit-equality exact: no -0 from sums of squares)
    unsigned c_[16];
    #pragma unroll
    for (int k = 0; k < 16; k++)
      c_[k] = (__float_as_uint(dl[k]) == wmaxbits) ? (unsigned)(tid + (k << 8)) : 0xFFFFFFFFu;
    unsigned q0 = min(c_[0], c_[1]),  q1 = min(c_[2], c_[3]);
    unsigned q2 = min(c_[4], c_[5]),  q3 = min(c_[6], c_[7]);
    unsigned q4 = min(c_[8], c_[9]),  q5 = min(c_[10], c_[11]);
    unsigned q6 = min(c_[12], c_[13]), q7 = min(c_[14], c_[15]);
    unsigned r0 = min(q0, q1), r1 = min(q2, q3), r2 = min(q4, q5), r3 = min(q6, q7);
    unsigned cand = min(min(r0, r1), min(r2, r3));
    cand = min(cand, dpp_mov_u<DPP_QUAD_XOR1>(cand));
    cand = min(cand, dpp_mov_u<DPP_QUAD_XOR2>(cand));
    cand = min(cand, dpp_mov_u<DPP_ROW_HALF_MIRROR>(cand));
    cand = min(cand, dpp_mov_u<DPP_ROW_MIRROR>(cand));
    cand = min(cand, dpp_mov_u<DPP_ROW_BCAST15>(cand));
    cand = min(cand, dpp_mov_u<DPP_ROW_BCAST31>(cand));  // lane63 = min j
    unsigned jmin = (unsigned)__builtin_amdgcn_readlane((int)cand, 63);
    // pre-barrier: fetch candidate coords (wave-uniform addr; latency hides
    // under the barrier wait) and publish them WITH the key.
    float4 cc = S->C[jmin];
    unsigned long long key = ((unsigned long long)wmaxbits << 32) |
                             (unsigned long long)(NPTS - 1 - jmin);
    const int p = t & 1;
    if (lane == 0) { S->slots[p][w].c = cc; S->slots[p][w].key = key; }
    __syncthreads();
    unsigned long long k0 = S->slots[p][0].key, k1 = S->slots[p][1].key;
    unsigned long long k2 = S->slots[p][2].key, k3 = S->slots[p][3].key;
    float4 cA = S->slots[p][0].c, cB = S->slots[p][1].c;
    float4 cC = S->slots[p][2].c, cD = S->slots[p][3].c;
    bool b1 = k1 > k0; unsigned long long ka = b1 ? k1 : k0; float4 ca = sel4(b1, cB, cA);
    bool b2 = k3 > k2; unsigned long long kb = b2 ? k3 : k2; float4 cb = sel4(b2, cD, cC);
    bool b3 = kb > ka; unsigned long long kbest = b3 ? kb : ka; float4 cbest = sel4(b3, cb, ca);
    f = NPTS - 1 - (int)(kbest & 0xFFFFFFFFull);
    cx = cbest.x; cy = cbest.y; cz = cbest.z;
  }
  __syncthreads();
  for (int i = tid; i < NPOINT; i += 256) cidx[b * NPOINT + i] = S->cidxS[i];
}

// PROJ-MLP: 64 blocks x 512 rows (2 rows/thread). Bit-identical MLP op order
// (h3 == mfeat row), writes mfeat and P = [xyz,h3]@A. (unchanged from R9)
__device__ void projmlp_body(char* smemRaw, const float* __restrict__ pts,
    const float* __restrict__ W0, const float* __restrict__ B0, const float* __restrict__ G0, const float* __restrict__ E0,
    const float* __restrict__ W1, const float* __restrict__ B1, const float* __restrict__ G1, const float* __restrict__ E1,
    const float* __restrict__ W2, const float* __restrict__ B2, const float* __restrict__ G2, const float* __restrict__ E2,
    const float* __restrict__ Aatt,
    float* __restrict__ mfeat, float* __restrict__ P) {
  ProjS* S = (ProjS*)smemRaw;
  const float INVS = 0.99999500003750f;            // 1/sqrt(1+1e-5)
  const int t = threadIdx.x;
  for (int i = t; i < 131 * 128; i += 256) S->As[i] = Aatt[i];
  for (int i = t; i < 4096; i += 256) { S->w0[i] = W0[i]; S->w1[i] = W1[i]; }
  for (int i = t; i < 8192; i += 256) S->w2[i] = W2[i];
  if (t < 64) {
    S->bb0[t] = B0[t]; S->ss0[t] = G0[t] * INVS; S->ee0[t] = E0[t];
    S->bb1[t] = B1[t]; S->ss1[t] = G1[t] * INVS; S->ee1[t] = E1[t];
  }
  if (t < 128) { S->bb2[t] = B2[t]; S->ss2[t] = G2[t] * INVS; S->ee2[t] = E2[t]; }
  __syncthreads();

  const int pb = blockIdx.x - 8;                   // 0..63
  for (int rr = 0; rr < 2; rr++) {
    const size_t r = (size_t)pb * 512 + rr * 256 + t;   // row 0..32767
    const float* xr = pts + r * PTDIM + 3;
    float x[64];
    #pragma unroll
    for (int c = 0; c < 64; c++) x[c] = xr[c];

    float h1[64];
    #pragma unroll
    for (int o = 0; o < 64; o++) {
      float acc = S->bb0[o];
      #pragma unroll
      for (int c = 0; c < 64; c += 4) {
        float4 wv = *(const float4*)&S->w0[o * 64 + c];
        acc = fmaf(wv.x, x[c], acc);
        acc = fmaf(wv.y, x[c + 1], acc);
        acc = fmaf(wv.z, x[c + 2], acc);
        acc = fmaf(wv.w, x[c + 3], acc);
      }
      h1[o] = fmaxf(fmaf(acc, S->ss0[o], S->ee0[o]), 0.0f);
    }
    float h2[64];
    #pragma unroll
    for (int o = 0; o < 64; o++) {
      float acc = S->bb1[o];
      #pragma unroll
      for (int c = 0; c < 64; c += 4) {
        float4 wv = *(const float4*)&S->w1[o * 64 + c];
        acc = fmaf(wv.x, h1[c], acc);
        acc = fmaf(wv.y, h1[c + 1], acc);
        acc = fmaf(wv.z, h1[c + 2], acc);
        acc = fmaf(wv.w, h1[c + 3], acc);
      }
      h2[o] = fmaxf(fmaf(acc, S->ss1[o], S->ee1[o]), 0.0f);
    }
    float h3[128];
    float* orow = mfeat + r * 128;
    #pragma unroll
    for (int o = 0; o < 128; o += 4) {
      float a0 = S->bb2[o], a1 = S->bb2[o + 1], a2 = S->bb2[o + 2], a3 = S->bb2[o + 3];
      #pragma unroll
      for (int c = 0; c < 64; c += 4) {
        float4 wv0 = *(const float4*)&S->w2[(o    ) * 64 + c];
        float4 wv1 = *(const float4*)&S->w2[(o + 1) * 64 + c];
        float4 wv2 = *(const float4*)&S->w2[(o + 2) * 64 + c];
        float4 wv3 = *(const float4*)&S->w2[(o + 3) * 64 + c];
        a0 = fmaf(wv0.x, h2[c], a0); a0 = fmaf(wv0.y, h2[c+1], a0); a0 = fmaf(wv0.z, h2[c+2], a0); a0 = fmaf(wv0.w, h2[c+3], a0);
        a1 = fmaf(wv1.x, h2[c], a1); a1 = fmaf(wv1.y, h2[c+1], a1); a1 = fmaf(wv1.z, h2[c+2], a1); a1 = fmaf(wv1.w, h2[c+3], a1);
        a2 = fmaf(wv2.x, h2[c], a2); a2 = fmaf(wv2.y, h2[c+1], a2); a2 = fmaf(wv2.z, h2[c+2], a2); a2 = fmaf(wv2.w, h2[c+3], a2);
        a3 = fmaf(wv3.x, h2[c], a3); a3 = fmaf(wv3.y, h2[c+1], a3); a3 = fmaf(wv3.z, h2[c+2], a3); a3 = fmaf(wv3.w, h2[c+3], a3);
      }
      float4 ov;
      ov.x = fmaxf(fmaf(a0, S->ss2[o    ], S->ee2[o    ]), 0.0f);
      ov.y = fmaxf(fmaf(a1, S->ss2[o + 1], S->ee2[o + 1]), 0.0f);
      ov.z = fmaxf(fmaf(a2, S->ss2[o + 2], S->ee2[o + 2]), 0.0f);
      ov.w = fmaxf(fmaf(a3, S->ss2[o + 3], S->ee2[o + 3]), 0.0f);
      h3[o] = ov.x; h3[o + 1] = ov.y; h3[o + 2] = ov.z; h3[o + 3] = ov.w;
      *(float4*)(orow + o) = ov;
    }
    const float* pr = pts + r * PTDIM;
    float x0 = pr[0], y0 = pr[1], z0 = pr[2];
    float* prow = P + r * 128;
    for (int grp = 0; grp < 4; grp++) {
      const int g0 = grp * 32;
      float acc[32];
      #pragma unroll
      for (int j = 0; j < 32; j++) {
        float a0 = S->As[0 * 128 + g0 + j];
        float a1 = S->As[1 * 128 + g0 + j];
        float a2 = S->As[2 * 128 + g0 + j];
        acc[j] = fmaf(z0, a2, fmaf(y0, a1, x0 * a0));
      }
      #pragma unroll
      for (int c = 0; c < 128; c++) {
        float s = h3[c];
        const float* arow = &S->As[(3 + c) * 128 + g0];
        #pragma unroll
        for (int j = 0; j < 32; j += 4) {
          float4 a = *(const float4*)&arow[j];
          acc[j]   = fmaf(s, a.x, acc[j]);
          acc[j+1] = fmaf(s, a.y, acc[j+1]);
          acc[j+2] = fmaf(s, a.z, acc[j+2]);
          acc[j+3] = fmaf(s, a.w, acc[j+3]);
        }
      }
      #pragma unroll
      for (int j = 0; j < 32; j += 4)
        *(float4*)(prow + g0 + j) = make_float4(acc[j], acc[j+1], acc[j+2], acc[j+3]);
    }
  }
}

__global__ __launch_bounds__(256) void f1_kernel(const float* __restrict__ pts,
    const float* __restrict__ W0, const float* __restrict__ B0, const float* __restrict__ G0, const float* __restrict__ E0,
    const float* __restrict__ W1, const float* __restrict__ B1, const float* __restrict__ G1, const float* __restrict__ E1,
    const float* __restrict__ W2, const float* __restrict__ B2, const float* __restrict__ G2, const float* __restrict__ E2,
    const float* __restrict__ Aatt,
    float* __restrict__ mfeat, float* __restrict__ P, int* __restrict__ cidx,
    float* __restrict__ X, float* __restrict__ Y, float* __restrict__ Z) {
  __shared__ __align__(16) char smem[F1_SMEM];
  if (blockIdx.x < 8)
    fps_body(smem, pts, cidx, X, Y, Z);
  else
    projmlp_body(smem, pts, W0, B0, G0, E0, W1, B1, G1, E1, W2, B2, G2, E2,
                 Aatt, mfeat, P);
}

// ---------------------------------------------------------------------------
// F23: FUSED ball-query + attention. 2048 blocks; each block's 4 waves do
// ballq for 4 centers (gidx stays in LDS — no global roundtrip), Pc rows and
// center xyz prefetched during ballq; then one barrier and 4 sequential attn
// phases using all 256 threads. Saves a launch + all gidx global traffic.
// ---------------------------------------------------------------------------
__global__ __launch_bounds__(256) void f23_kernel(
    const float* __restrict__ X, const float* __restrict__ Y, const float* __restrict__ Z,
    const int* __restrict__ cidx,
    const float* __restrict__ mfeat, const float* __restrict__ P,
    float* __restrict__ out) {
  __shared__ float dbuf[4][512];
  __shared__ int   ibuf[4][512];
  __shared__ int   gidxS[4][NSAMPLE];
  __shared__ float pcS[4][128];
  __shared__ float cxyzS[4][3];
  const int t = threadIdx.x;
  const int w = t >> 6, lane = t & 63;
  const int batch = blockIdx.x & 7;                // batch-per-XCD swizzle
  const int grpI = blockIdx.x >> 3;                // 0..255
  const int pcBase = batch * 1024 + grpI * 4;
  const int pc = pcBase + w;
  const float* Xb = X + batch * NPTS;
  const float* Yb = Y + batch * NPTS;
  const float* Zb = Z + batch * NPTS;
  const int cI = cidx[pc];
  const float cx = Xb[cI], cy = Yb[cI], cz = Zb[cI];
  if (lane == 0) { cxyzS[w][0] = cx; cxyzS[w][1] = cy; cxyzS[w][2] = cz; }
  // prefetch Pc row for this wave's center (2 floats/lane)
  {
    const float* pcrow = P + ((size_t)batch * NPTS + cI) * 128;
    pcS[w][lane] = pcrow[lane];
    pcS[w][lane + 64] = pcrow[lane + 64];
  }
  // ---- ball query (exact f32 replication; stable-(d,idx) 32-smallest) ----
  const float sc = __fadd_rn(__fadd_rn(__fmul_rn(cx, cx), __fmul_rn(cy, cy)), __fmul_rn(cz, cz));
  const float R2 = 0.04f;
  int cnt = 0;                                     // wave-uniform
  for (int rr = 0; rr < 16; rr++) {
    const int base = rr * 256 + lane * 4;
    float4 px4 = *(const float4*)(Xb + base);
    float4 py4 = *(const float4*)(Yb + base);
    float4 pz4 = *(const float4*)(Zb + base);
    #pragma unroll
    for (int e = 0; e < 4; e++) {
      float px = e == 0 ? px4.x : e == 1 ? px4.y : e == 2 ? px4.z : px4.w;
      float py = e == 0 ? py4.x : e == 1 ? py4.y : e == 2 ? py4.z : py4.w;
      float pz = e == 0 ? pz4.x : e == 1 ? pz4.y : e == 2 ? pz4.z : pz4.w;
      float dot = __fadd_rn(__fadd_rn(__fmul_rn(cx, px), __fmul_rn(cy, py)), __fmul_rn(cz, pz));
      float sx  = __fadd_rn(__fadd_rn(__fmul_rn(px, px), __fmul_rn(py, py)), __fmul_rn(pz, pz));
      float d   = __fadd_rn(__fadd_rn(__fmul_rn(-2.0f, dot), sc), sx);
      bool pred = !(d > R2);
      unsigned long long mask = __ballot(pred);
      if (pred) {
        int pos = cnt + (int)__popcll(mask & ((1ull << lane) - 1ull));
        if (pos < 512) { dbuf[w][pos] = d; ibuf[w][pos] = base + e; }
      }
      cnt += (int)__popcll(mask);
    }
  }
  const int K = cnt < 512 ? cnt : 512;
  unsigned long long kk[8];
  #pragma unroll
  for (int k = 0; k < 8; k++) {
    int pos = lane + 64 * k;
    if (pos < K)
      kk[k] = ((unsigned long long)fmap(dbuf[w][pos]) << 32) | (unsigned)ibuf[w][pos];
    else
      kk[k] = ((unsigned long long)FMAP_INF << 32) | 0x7fffffffu;
  }
  int first = 0;
  for (int it = 0; it < NSAMPLE; it++) {
    unsigned long long best = kk[0];
    #pragma unroll
    for (int k = 1; k < 8; k++) if (kk[k] < best) best = kk[k];
    unsigned hi = (unsigned)(best >> 32), lo = (unsigned)best;
    dpp_min2<DPP_QUAD_XOR1>(hi, lo);
    dpp_min2<DPP_QUAD_XOR2>(hi, lo);
    dpp_min2<DPP_ROW_HALF_MIRROR>(hi, lo);
    dpp_min2<DPP_ROW_MIRROR>(hi, lo);
    dpp_min2<DPP_ROW_BCAST15>(hi, lo);
    dpp_min2<DPP_ROW_BCAST31>(hi, lo);             // lane63 = wave min
    unsigned blo = (unsigned)__builtin_amdgcn_readlane((int)lo, 63);
    #pragma unroll
    for (int k = 0; k < 8; k++)
      if ((unsigned)kk[k] == blo)
        kk[k] = (kk[k] & 0xFFFFFFFFull) | ((unsigned long long)FMAP_INF << 32);
    if (it == 0) first = (int)blo;
    if (lane == 0) gidxS[w][it] = (it < K) ? (int)blo : first;
  }
  __syncthreads();
  // ---- attention for the block's 4 centers (all 256 threads each) ----
  const int n = t & 31, q = t >> 5;                // q: 0..7, 16 channels each
  for (int s = 0; s < 4; s++) {
    const int pcA = pcBase + s;
    const int g = gidxS[s][n];
    const float* Pg = P + ((size_t)batch * NPTS + g) * 128 + q * 16;
    const float* Gf = mfeat + ((size_t)batch * NPTS + g) * 128 + q * 16;
    float a[16], gfv[16];
    #pragma unroll
    for (int k = 0; k < 4; k++) {
      float4 vg = *(const float4*)(Pg + 4 * k);
      float4 vc = *(const float4*)&pcS[s][q * 16 + 4 * k];  // LDS broadcast
      float4 vf = *(const float4*)(Gf + 4 * k);
      a[4*k]   = vg.x - vc.x; a[4*k+1] = vg.y - vc.y;
      a[4*k+2] = vg.z - vc.z; a[4*k+3] = vg.w - vc.w;
      gfv[4*k] = vf.x; gfv[4*k+1] = vf.y; gfv[4*k+2] = vf.z; gfv[4*k+3] = vf.w;
    }
    #pragma unroll
    for (int j = 0; j < 16; j++) a[j] = a[j] >= 0.0f ? a[j] : 0.2f * a[j];
    float e[16], ssum[16], num[16];
    #pragma unroll
    for (int j = 0; j < 16; j++) {
      float mx = red32_max(a[j]);
      e[j] = expf(a[j] - mx);
    }
    #pragma unroll
    for (int j = 0; j < 16; j++) ssum[j] = red32_sum(e[j]);
    #pragma unroll
    for (int j = 0; j < 16; j++) num[j] = red32_sum(e[j] * gfv[j]);
    if (n == 0) {
      float* orow = out + (size_t)pcA * 131;
      #pragma unroll
      for (int j = 0; j < 16; j++) orow[3 + q * 16 + j] = num[j] / ssum[j];
      if (q == 0) {
        orow[0] = cxyzS[s][0]; orow[1] = cxyzS[s][1]; orow[2] = cxyzS[s][2];
      }
    }
  }
}

// ---------------------------------------------------------------------------
extern "C" void kernel_launch(void* const* d_in, const int* in_sizes, int n_in,
                              void* d_out, int out_size, void* d_ws, size_t ws_size,
                              hipStream_t stream) {
  const float* points = (const float*)d_in[0];
  const float* W0 = (const float*)d_in[1];
  const float* B0 = (const float*)d_in[2];
  const float* G0 = (const float*)d_in[3];
  const float* E0 = (const float*)d_in[4];
  const float* W1 = (const float*)d_in[5];
  const float* B1 = (const float*)d_in[6];
  const float* G1 = (const float*)d_in[7];
  const float* E1 = (const float*)d_in[8];
  const float* W2 = (const float*)d_in[9];
  const float* B2 = (const float*)d_in[10];
  const float* G2 = (const float*)d_in[11];
  const float* E2 = (const float*)d_in[12];
  const float* Aatt = (const float*)d_in[13];
  float* out = (float*)d_out;

  // workspace (floats): mfeat 4.19M | P 4.19M | X/Y/Z 3*32k | cidx 8k  (~34 MB)
  float* mfeat = (float*)d_ws;
  float* Pw = mfeat + (size_t)NBATCH * NPTS * 128;
  float* Xw = Pw + (size_t)NBATCH * NPTS * 128;
  float* Yw = Xw + NBATCH * NPTS;
  float* Zw = Yw + NBATCH * NPTS;
  int* cidxw = (int*)(Zw + NBATCH * NPTS);

  f1_kernel<<<8 + 64, 256, 0, stream>>>(points,
      W0, B0, G0, E0, W1, B1, G1, E1, W2, B2, G2, E2, Aatt,
      mfeat, Pw, cidxw, Xw, Yw, Zw);
  f23_kernel<<<NBATCH * NPOINT / 4, 256, 0, stream>>>(Xw, Yw, Zw, cidxw,
                                                      mfeat, Pw, out);
}